// Round 1
// baseline (116.993 us; speedup 1.0000x reference)
//
#include <hip/hip_runtime.h>
#include <hip/hip_bf16.h>
#include <stdint.h>

#define NHEADS 8
#define DHEAD 32
#define BB 2
#define LL 512
#define HH 256

__device__ __forceinline__ float bf_lo(unsigned u){ return __uint_as_float(u << 16); }
__device__ __forceinline__ float bf_hi(unsigned u){ return __uint_as_float(u & 0xffff0000u); }
__device__ __forceinline__ unsigned short f2bf(float f){
    unsigned u = __float_as_uint(f);
    u += 0x7fffu + ((u >> 16) & 1u);   // RNE
    return (unsigned short)(u >> 16);
}
__device__ __forceinline__ void unpack8(uint4 u, float* f){
    f[0]=bf_lo(u.x); f[1]=bf_hi(u.x);
    f[2]=bf_lo(u.y); f[3]=bf_hi(u.y);
    f[4]=bf_lo(u.z); f[5]=bf_hi(u.z);
    f[6]=bf_lo(u.w); f[7]=bf_hi(u.w);
}

// ---------------------------------------------------------------------------
// K1: all four projections.  grid = 4 gemms x 128 row-blocks (8 rows each).
// out = (in @ W.T + bias) * scale, stored bf16.
//   g0: q  = (e1 @ Wq.T + bq) * 1/sqrt(32)
//   g1: k  =  e2 @ Wk.T + bk
//   g2: h1 =  e1 @ W1[:, :H].T
//   g3: h2b=  e2 @ W1[:, H:].T + b1
// ---------------------------------------------------------------------------
__global__ __launch_bounds__(256) void k_proj(
    const float* __restrict__ e1, const float* __restrict__ e2,
    const float* __restrict__ ipw, const float* __restrict__ ipb,
    const float* __restrict__ W1, const float* __restrict__ b1,
    unsigned short* __restrict__ wq, unsigned short* __restrict__ wk,
    unsigned short* __restrict__ wh1, unsigned short* __restrict__ wh2)
{
    __shared__ __align__(16) float es[8 * HH];
    const int t = threadIdx.x;
    const int g = blockIdx.x >> 7;
    const int row0 = (blockIdx.x & 127) << 3;
    const float* in = (g == 0 || g == 2) ? e1 : e2;
    {
        const float4* src = (const float4*)(in + (size_t)row0 * HH);
        float4* dst = (float4*)es;
        dst[t]       = src[t];
        dst[t + 256] = src[t + 256];
    }
    __syncthreads();
    const float* wrow; float bias = 0.f; float scale = 1.0f;
    if (g == 0)      { wrow = ipw + t * HH;            bias = ipb[t];      scale = 0.17677669529663689f; }
    else if (g == 1) { wrow = ipw + (HH + t) * HH;     bias = ipb[HH + t]; }
    else if (g == 2) { wrow = W1 + t * (2 * HH); }
    else             { wrow = W1 + t * (2 * HH) + HH;  bias = b1[t]; }

    float acc[8];
    #pragma unroll
    for (int r = 0; r < 8; r++) acc[r] = bias;
    #pragma unroll 4
    for (int kc = 0; kc < 64; kc++){
        float4 w4 = ((const float4*)wrow)[kc];
        #pragma unroll
        for (int r = 0; r < 8; r++){
            float4 e4 = ((const float4*)(es + r * HH))[kc];   // uniform addr -> LDS broadcast
            acc[r] = fmaf(e4.x, w4.x, fmaf(e4.y, w4.y, fmaf(e4.z, w4.z, fmaf(e4.w, w4.w, acc[r]))));
        }
    }
    unsigned short* outp = (g == 0) ? wq : ((g == 1) ? wk : ((g == 2) ? wh1 : wh2));
    #pragma unroll
    for (int r = 0; r < 8; r++)
        outp[(size_t)(row0 + r) * HH + t] = f2bf(acc[r] * scale);
}

// ---------------------------------------------------------------------------
// K2a: logits[b,i,h,j] = qh . kh   (scale pre-folded into q), bf16 out.
// grid = B*NH*8*8 = 1024 blocks; 64x64 tile per block, 4x4 per thread, K=32.
// LDS bf16 tiles, stride 40 ushorts + XOR part-swizzle -> <=2-way conflicts.
// ---------------------------------------------------------------------------
__global__ __launch_bounds__(256) void k_logits(
    const unsigned short* __restrict__ wq, const unsigned short* __restrict__ wk,
    unsigned short* __restrict__ lg)
{
    __shared__ __align__(16) unsigned short Qs[64 * 40];
    __shared__ __align__(16) unsigned short Ks[64 * 40];
    const int t = threadIdx.x;
    const int blk = blockIdx.x;
    const int jt = blk & 7, it = (blk >> 3) & 7, h = (blk >> 6) & 7, b = blk >> 9;
    const int i0 = it * 64, j0 = jt * 64;
    {
        const int row = t >> 2, part = t & 3;
        const int sw = part ^ ((row >> 2) & 3);
        const uint4* qsrc = (const uint4*)(wq + ((size_t)(b * LL + i0 + row)) * HH + h * DHEAD);
        const uint4* ksrc = (const uint4*)(wk + ((size_t)(b * LL + j0 + row)) * HH + h * DHEAD);
        *(uint4*)(Qs + row * 40 + sw * 8) = qsrc[part];
        *(uint4*)(Ks + row * 40 + sw * 8) = ksrc[part];
    }
    __syncthreads();
    const int tx = t & 15, ty = t >> 4;
    float acc[4][4] = {};
    #pragma unroll
    for (int kc = 0; kc < 4; kc++){
        float qf[4][8], kf[4][8];
        #pragma unroll
        for (int r = 0; r < 4; r++){
            uint4 qu = *(const uint4*)(Qs + (ty * 4 + r) * 40 + (kc ^ (ty & 3)) * 8);
            unpack8(qu, qf[r]);
            uint4 ku = *(const uint4*)(Ks + (tx * 4 + r) * 40 + (kc ^ (tx & 3)) * 8);
            unpack8(ku, kf[r]);
        }
        #pragma unroll
        for (int ii = 0; ii < 4; ii++)
        #pragma unroll
        for (int jj = 0; jj < 4; jj++){
            float s = acc[ii][jj];
            #pragma unroll
            for (int e = 0; e < 8; e++) s = fmaf(qf[ii][e], kf[jj][e], s);
            acc[ii][jj] = s;
        }
    }
    #pragma unroll
    for (int ii = 0; ii < 4; ii++){
        const int i = i0 + ty * 4 + ii;
        ushort4 v;
        v.x = f2bf(acc[ii][0]); v.y = f2bf(acc[ii][1]);
        v.z = f2bf(acc[ii][2]); v.w = f2bf(acc[ii][3]);
        *(ushort4*)(lg + (((size_t)(b * LL + i) * NHEADS + h) << 9) + j0 + tx * 4) = v;
    }
}

// ---------------------------------------------------------------------------
// K2b: per (b,i): 8 softmaxes over j=512, head-mean -> attn_weights row.
// head h owns threads 32h..32h+31 (within one wave -> shfl reductions).
// exp recomputed in the output pass (avoids strided LDS writes).
// ---------------------------------------------------------------------------
__global__ __launch_bounds__(256) void k_softmax(
    const unsigned short* __restrict__ lg, float* __restrict__ outA)
{
    __shared__ float ms[8], invs[8];
    const int bi = blockIdx.x;            // b*512+i
    const int t = threadIdx.x;
    const int h = t >> 5, g = t & 31;
    const uint4* src = (const uint4*)(lg + (size_t)bi * 4096 + h * 512 + g * 16);
    uint4 u0 = src[0], u1 = src[1];
    float v[16];
    unpack8(u0, v); unpack8(u1, v + 8);
    float m = v[0];
    #pragma unroll
    for (int e = 1; e < 16; e++) m = fmaxf(m, v[e]);
    #pragma unroll
    for (int mask = 1; mask < 32; mask <<= 1) m = fmaxf(m, __shfl_xor(m, mask, 64));
    float s = 0.f;
    #pragma unroll
    for (int e = 0; e < 16; e++) s += __expf(v[e] - m);
    #pragma unroll
    for (int mask = 1; mask < 32; mask <<= 1) s += __shfl_xor(s, mask, 64);
    if (g == 0){ ms[h] = m; invs[h] = 1.0f / (8.0f * s); }
    __syncthreads();
    float mm[8], ww[8];
    #pragma unroll
    for (int hh = 0; hh < 8; hh++){ mm[hh] = ms[hh]; ww[hh] = invs[hh]; }
    #pragma unroll
    for (int jj = 0; jj < 2; jj++){
        const int j = t + jj * 256;
        float o = 0.f;
        #pragma unroll
        for (int hh = 0; hh < 8; hh++){
            float lv = bf_lo((unsigned)lg[(size_t)bi * 4096 + hh * 512 + j]);
            o = fmaf(__expf(lv - mm[hh]), ww[hh], o);
        }
        outA[(size_t)bi * 512 + j] = o;
    }
}

// ---------------------------------------------------------------------------
// K3: match_scores[b,i,j] = sigmoid( sum_h relu(h1[i,h]+h2b[j,h]) * w2[h] + b2 )
// grid = 2 * 16 * 16 = 512 blocks; 32x32 pair tile, 2x2 per thread.
// h1/h2b staged bf16 in LDS (stride 264 ushorts); h2 cols XOR-quad-swizzled.
// ---------------------------------------------------------------------------
__global__ __launch_bounds__(256) void k_match(
    const unsigned short* __restrict__ wh1, const unsigned short* __restrict__ wh2,
    const float* __restrict__ W2, const float* __restrict__ b2,
    float* __restrict__ outM)
{
    __shared__ __align__(16) unsigned short h1s[32 * 264];
    __shared__ __align__(16) unsigned short h2s[32 * 264];
    __shared__ __align__(16) float w2s[HH];
    const int t = threadIdx.x;
    const int blk = blockIdx.x;
    const int b = blk >> 8, it = (blk >> 4) & 15, jt = blk & 15;
    const int i0 = it * 32, j0 = jt * 32;
    w2s[t] = W2[t];
    {
        const uint4* s1 = (const uint4*)(wh1 + ((size_t)(b * LL + i0)) * HH);
        const uint4* s2 = (const uint4*)(wh2 + ((size_t)(b * LL + j0)) * HH);
        #pragma unroll
        for (int p = 0; p < 4; p++){
            const int idx = p * 256 + t;
            const int row = idx >> 5, col = idx & 31;
            ((uint4*)h1s)[row * 33 + col] = s1[idx];
            const int colw = col ^ ((row >> 1) & 7);
            ((uint4*)h2s)[row * 33 + colw] = s2[idx];
        }
    }
    __syncthreads();
    const int ti = t >> 4, tj = t & 15;
    const int sw = tj & 7;
    float a00 = 0.f, a01 = 0.f, a10 = 0.f, a11 = 0.f;
    #pragma unroll 4
    for (int hc = 0; hc < 32; hc++){
        uint4 ua = ((const uint4*)h1s)[(ti * 2    ) * 33 + hc];
        uint4 ub = ((const uint4*)h1s)[(ti * 2 + 1) * 33 + hc];
        uint4 uc = ((const uint4*)h2s)[(tj * 2    ) * 33 + (hc ^ sw)];
        uint4 ud = ((const uint4*)h2s)[(tj * 2 + 1) * 33 + (hc ^ sw)];
        float4 w0 = ((const float4*)w2s)[hc * 2];
        float4 w1 = ((const float4*)w2s)[hc * 2 + 1];
        float fa[8], fb[8], fc[8], fd[8];
        unpack8(ua, fa); unpack8(ub, fb); unpack8(uc, fc); unpack8(ud, fd);
        const float wv[8] = {w0.x, w0.y, w0.z, w0.w, w1.x, w1.y, w1.z, w1.w};
        #pragma unroll
        for (int e = 0; e < 8; e++){
            a00 = fmaf(fmaxf(fa[e] + fc[e], 0.f), wv[e], a00);
            a01 = fmaf(fmaxf(fa[e] + fd[e], 0.f), wv[e], a01);
            a10 = fmaf(fmaxf(fb[e] + fc[e], 0.f), wv[e], a10);
            a11 = fmaf(fmaxf(fb[e] + fd[e], 0.f), wv[e], a11);
        }
    }
    const float bb2 = b2[0];
    const int i = i0 + ti * 2, j = j0 + tj * 2;
    float* orow = outM + ((size_t)(b * LL + i)) * LL + j;
    float s00 = 1.f / (1.f + __expf(-(a00 + bb2)));
    float s01 = 1.f / (1.f + __expf(-(a01 + bb2)));
    float s10 = 1.f / (1.f + __expf(-(a10 + bb2)));
    float s11 = 1.f / (1.f + __expf(-(a11 + bb2)));
    *(float2*)orow        = make_float2(s00, s01);
    *(float2*)(orow + LL) = make_float2(s10, s11);
}

extern "C" void kernel_launch(void* const* d_in, const int* in_sizes, int n_in,
                              void* d_out, int out_size, void* d_ws, size_t ws_size,
                              hipStream_t stream)
{
    const float* e1  = (const float*)d_in[0];
    const float* e2  = (const float*)d_in[1];
    const float* ipw = (const float*)d_in[2];
    const float* ipb = (const float*)d_in[3];
    const float* W1  = (const float*)d_in[4];
    const float* b1  = (const float*)d_in[5];
    const float* W2  = (const float*)d_in[6];
    const float* b2  = (const float*)d_in[7];
    float* outA = (float*)d_out;                       // (B,L1,L2) attn weights
    float* outM = outA + (size_t)BB * LL * LL;         // (B,L1,L2) match scores

    unsigned short* ws  = (unsigned short*)d_ws;
    unsigned short* wq  = ws;                  // 262144 bf16 (q, pre-scaled)
    unsigned short* wk  = ws + 262144;         // k
    unsigned short* wh1 = ws + 524288;         // h1
    unsigned short* wh2 = ws + 786432;         // h2 + b1
    unsigned short* lg  = ws + 1048576;        // logits (b,i,h,j): 4.19M bf16

    hipLaunchKernelGGL(k_proj,    dim3(512),  dim3(256), 0, stream,
                       e1, e2, ipw, ipb, W1, b1, wq, wk, wh1, wh2);
    hipLaunchKernelGGL(k_logits,  dim3(1024), dim3(256), 0, stream, wq, wk, lg);
    hipLaunchKernelGGL(k_softmax, dim3(1024), dim3(256), 0, stream, lg, outA);
    hipLaunchKernelGGL(k_match,   dim3(512),  dim3(256), 0, stream,
                       wh1, wh2, (const float*)W2, (const float*)b2, outM);
}

// Round 4
// 111.387 us; speedup vs baseline: 1.0503x; 1.0503x over previous
//
#include <hip/hip_runtime.h>
#include <hip/hip_fp16.h>
#include <stdint.h>

typedef _Float16 f16x8 __attribute__((ext_vector_type(8)));
typedef _Float16 f16x2 __attribute__((ext_vector_type(2)));
typedef float f32x4 __attribute__((ext_vector_type(4)));

#define LL 512
#define HH 256

__device__ __forceinline__ unsigned pkrtz(float a, float b){
    return __builtin_bit_cast(unsigned, __builtin_amdgcn_cvt_pkrtz(a, b));
}

#if __has_builtin(__builtin_amdgcn_fdot2)
__device__ __forceinline__ float fdot2(f16x2 x, f16x2 w, float acc){
    return __builtin_amdgcn_fdot2(x, w, acc, false);
}
#else
__device__ __forceinline__ float fdot2(f16x2 x, f16x2 w, float acc){
    return fmaf((float)x[0], (float)w[0], fmaf((float)x[1], (float)w[1], acc));
}
#endif

// ---------------------------------------------------------------------------
// K1: four projections as MFMA f16 GEMMs. out = (in @ W.T + bias) * scale, f16.
// grid = 4 gemms x 16 m-tiles x 4 n-tiles = 256 blocks; 64x64 tile, K=256.
// Stage f32->f16 into LDS with 16B-chunk XOR swizzle (chunk ^= row&7).
//   g0: q  = (e1 @ Wq.T + bq) * 1/sqrt(32)     g1: k  = e2 @ Wk.T + bk
//   g2: h1 = e1 @ W1[:, :H].T                  g3: h2 = e2 @ W1[:, H:].T + b1
// ---------------------------------------------------------------------------
__global__ __launch_bounds__(256) void k_proj(
    const float* __restrict__ e1, const float* __restrict__ e2,
    const float* __restrict__ ipw, const float* __restrict__ ipb,
    const float* __restrict__ W1, const float* __restrict__ b1,
    _Float16* __restrict__ wq, _Float16* __restrict__ wk,
    _Float16* __restrict__ wh1, _Float16* __restrict__ wh2)
{
    __shared__ __align__(16) _Float16 As[64 * 256];
    __shared__ __align__(16) _Float16 Bs[64 * 256];
    const int t = threadIdx.x;
    const int blk = blockIdx.x;
    const int g = blk >> 6, mt = (blk >> 2) & 15, nt = blk & 3;
    const int m0 = mt * 64, n0 = nt * 64;
    const float* abase = (g == 0 || g == 2) ? e1 : e2;
    const float* bbase; int bstride;
    if (g == 0)      { bbase = ipw;         bstride = 256; }
    else if (g == 1) { bbase = ipw + 65536; bstride = 256; }
    else if (g == 2) { bbase = W1;          bstride = 512; }
    else             { bbase = W1 + 256;    bstride = 512; }

    #pragma unroll
    for (int s = 0; s < 8; s++){
        const int c = s * 256 + t;
        const int row = c >> 5, kg = c & 31;
        const int dst = row * 256 + ((kg ^ (row & 7)) << 3);
        {
            const float4* sa = (const float4*)(abase + (size_t)(m0 + row) * 256 + kg * 8);
            float4 a0 = sa[0], a1 = sa[1];
            uint4 pk = { pkrtz(a0.x, a0.y), pkrtz(a0.z, a0.w),
                         pkrtz(a1.x, a1.y), pkrtz(a1.z, a1.w) };
            *(uint4*)(As + dst) = pk;
        }
        {
            const float4* sb = (const float4*)(bbase + (size_t)(n0 + row) * bstride + kg * 8);
            float4 b0 = sb[0], b1v = sb[1];
            uint4 pk = { pkrtz(b0.x, b0.y), pkrtz(b0.z, b0.w),
                         pkrtz(b1v.x, b1v.y), pkrtz(b1v.z, b1v.w) };
            *(uint4*)(Bs + dst) = pk;
        }
    }
    __syncthreads();
    const int w = t >> 6, l = t & 63;
    const int lr = l & 15, lg = l >> 4;
    f32x4 acc[4] = {};
    const int brow = w * 16 + lr;
    #pragma unroll
    for (int kk = 0; kk < 8; kk++){
        const int cb = ((kk * 4 + lg) ^ (lr & 7)) << 3;   // swizzled 16B chunk
        f16x8 bf = *(const f16x8*)(Bs + brow * 256 + cb);
        #pragma unroll
        for (int ms = 0; ms < 4; ms++){
            f16x8 af = *(const f16x8*)(As + (ms * 16 + lr) * 256 + cb);
            acc[ms] = __builtin_amdgcn_mfma_f32_16x16x32_f16(af, bf, acc[ms], 0, 0, 0);
        }
    }
    const int n = n0 + w * 16 + lr;
    float bias = 0.f, scale = 1.f;
    if (g == 0)      { bias = ipb[n];       scale = 0.17677669529663689f; }
    else if (g == 1) { bias = ipb[256 + n]; }
    else if (g == 3) { bias = b1[n]; }
    _Float16* outp = (g == 0) ? wq : ((g == 1) ? wk : ((g == 2) ? wh1 : wh2));
    #pragma unroll
    for (int ms = 0; ms < 4; ms++)
        #pragma unroll
        for (int r = 0; r < 4; r++){
            const int m = m0 + ms * 16 + lg * 4 + r;
            outp[(size_t)m * 256 + n] = (_Float16)((acc[ms][r] + bias) * scale);
        }
}

// ---------------------------------------------------------------------------
// K2: fused logits+softmax+head-mean. grid = B*32 = 64 blocks, 4 waves each.
// Block owns a 16-row i-tile; wave w owns j-tiles {4p+w}. Q frags in regs
// (8 heads x f16x8). 3 MFMA passes: max -> sum -> normalized head-mean out.
// Cross-wave stat combine via tiny LDS arrays.
// ---------------------------------------------------------------------------
__global__ __launch_bounds__(256) void k_attn(
    const _Float16* __restrict__ wq, const _Float16* __restrict__ wk,
    float* __restrict__ outA)
{
    __shared__ float sm[4][8][16];
    __shared__ float fm[8][16];
    __shared__ float fi[8][16];
    const int t = threadIdx.x;
    const int b = blockIdx.x >> 5;
    const int i0 = (blockIdx.x & 31) << 4;
    const int w = t >> 6, l = t & 63, lr = l & 15, lg = l >> 4;

    const _Float16* qrow = wq + (size_t)(b * LL + i0 + lr) * HH + lg * 8;
    f16x8 q[8];
    #pragma unroll
    for (int h = 0; h < 8; h++) q[h] = *(const f16x8*)(qrow + h * 32);

    const _Float16* kbase = wk + (size_t)(b * LL) * HH + lg * 8;
    const f32x4 zero = {};
    float m2[8][4];

    // pass 1: per-(h,i) max over all j
    #pragma unroll
    for (int h = 0; h < 8; h++){
        float m4[4] = {-3e38f, -3e38f, -3e38f, -3e38f};
        for (int p = 0; p < 8; p++){
            const int j0 = (p * 4 + w) << 4;
            f16x8 kf = *(const f16x8*)(kbase + (size_t)(j0 + lr) * HH + h * 32);
            f32x4 a = __builtin_amdgcn_mfma_f32_16x16x32_f16(q[h], kf, zero, 0, 0, 0);
            #pragma unroll
            for (int r = 0; r < 4; r++) m4[r] = fmaxf(m4[r], a[r]);
        }
        #pragma unroll
        for (int r = 0; r < 4; r++){
            #pragma unroll
            for (int mask = 1; mask < 16; mask <<= 1)
                m4[r] = fmaxf(m4[r], __shfl_xor(m4[r], mask, 64));
        }
        if (lr == 0){
            #pragma unroll
            for (int r = 0; r < 4; r++) sm[w][h][lg * 4 + r] = m4[r];
        }
    }
    __syncthreads();
    if (t < 128){
        const int h = t >> 4, i = t & 15;
        fm[h][i] = fmaxf(fmaxf(sm[0][h][i], sm[1][h][i]),
                         fmaxf(sm[2][h][i], sm[3][h][i]));
    }
    __syncthreads();
    #pragma unroll
    for (int h = 0; h < 8; h++)
        #pragma unroll
        for (int r = 0; r < 4; r++) m2[h][r] = fm[h][lg * 4 + r];

    // pass 2: exp-sums
    #pragma unroll
    for (int h = 0; h < 8; h++){
        float s4[4] = {0.f, 0.f, 0.f, 0.f};
        for (int p = 0; p < 8; p++){
            const int j0 = (p * 4 + w) << 4;
            f16x8 kf = *(const f16x8*)(kbase + (size_t)(j0 + lr) * HH + h * 32);
            f32x4 a = __builtin_amdgcn_mfma_f32_16x16x32_f16(q[h], kf, zero, 0, 0, 0);
            #pragma unroll
            for (int r = 0; r < 4; r++) s4[r] += __expf(a[r] - m2[h][r]);
        }
        #pragma unroll
        for (int r = 0; r < 4; r++){
            #pragma unroll
            for (int mask = 1; mask < 16; mask <<= 1)
                s4[r] += __shfl_xor(s4[r], mask, 64);
        }
        if (lr == 0){
            #pragma unroll
            for (int r = 0; r < 4; r++) sm[w][h][lg * 4 + r] = s4[r];
        }
    }
    __syncthreads();
    if (t < 128){
        const int h = t >> 4, i = t & 15;
        fi[h][i] = 1.0f / (8.0f * (sm[0][h][i] + sm[1][h][i] + sm[2][h][i] + sm[3][h][i]));
    }
    __syncthreads();
    float iv[8][4];
    #pragma unroll
    for (int h = 0; h < 8; h++)
        #pragma unroll
        for (int r = 0; r < 4; r++) iv[h][r] = fi[h][lg * 4 + r];

    // pass 3: normalized head-mean, write attn
    for (int p = 0; p < 8; p++){
        const int j0 = (p * 4 + w) << 4;
        f32x4 mean = {};
        #pragma unroll
        for (int h = 0; h < 8; h++){
            f16x8 kf = *(const f16x8*)(kbase + (size_t)(j0 + lr) * HH + h * 32);
            f32x4 a = __builtin_amdgcn_mfma_f32_16x16x32_f16(q[h], kf, zero, 0, 0, 0);
            #pragma unroll
            for (int r = 0; r < 4; r++) mean[r] += __expf(a[r] - m2[h][r]) * iv[h][r];
        }
        #pragma unroll
        for (int r = 0; r < 4; r++)
            outA[(size_t)(b * LL + i0 + lg * 4 + r) * LL + j0 + lr] = mean[r];
    }
}

// ---------------------------------------------------------------------------
// K4: match_scores = sigmoid( sum_h relu(h1[i,h]+h2b[j,h]) . w2[h] + b2 )
// grid = 2 x 8 x 16 = 256 blocks (64i x 32j tile), 256 thr, per-thread 4x2.
// f16 packed math: v_pk_add_f16 + v_pk_max_f16 + v_dot2_f32_f16 (f32 accum)
// = 3 instrs per 2 h-elements. LDS chunks XOR-swizzled per read-set.
// ---------------------------------------------------------------------------
__global__ __launch_bounds__(256) void k_match(
    const _Float16* __restrict__ wh1, const _Float16* __restrict__ wh2,
    const float* __restrict__ W2, const float* __restrict__ b2,
    float* __restrict__ outM)
{
    __shared__ __align__(16) _Float16 h1s[64 * 256];
    __shared__ __align__(16) _Float16 h2s[32 * 256];
    __shared__ __align__(16) f16x2 w2s[128];
    const int t = threadIdx.x;
    const int blk = blockIdx.x;
    const int b = blk >> 7, it = (blk >> 4) & 7, jt = blk & 15;
    const int i0 = it * 64, j0 = jt * 32;
    if (t < 128){
        unsigned pk = pkrtz(W2[2 * t], W2[2 * t + 1]);
        w2s[t] = __builtin_bit_cast(f16x2, pk);
    }
    #pragma unroll
    for (int s = 0; s < 8; s++){
        const int c = s * 256 + t;
        const int row = c >> 5, hc = c & 31;
        uint4 v = *(const uint4*)(wh1 + (size_t)(b * LL + i0 + row) * HH + hc * 8);
        *(uint4*)(h1s + row * 256 + ((hc ^ ((row >> 2) & 7)) << 3)) = v;
    }
    #pragma unroll
    for (int s = 0; s < 4; s++){
        const int c = s * 256 + t;
        const int row = c >> 5, hc = c & 31;
        uint4 v = *(const uint4*)(wh2 + (size_t)(b * LL + j0 + row) * HH + hc * 8);
        *(uint4*)(h2s + row * 256 + ((hc ^ ((row >> 1) & 7)) << 3)) = v;
    }
    __syncthreads();
    const int ti = t >> 4, tj = t & 15;
    float acc[4][2] = {};
    for (int hc = 0; hc < 32; hc++){
        unsigned ua[4][4], uc[2][4], uw[4];
        {
            uint4 v;
            #pragma unroll
            for (int rr = 0; rr < 4; rr++){
                v = *(const uint4*)(h1s + (ti * 4 + rr) * 256 + ((hc ^ (ti & 7)) << 3));
                ua[rr][0] = v.x; ua[rr][1] = v.y; ua[rr][2] = v.z; ua[rr][3] = v.w;
            }
            #pragma unroll
            for (int rr = 0; rr < 2; rr++){
                v = *(const uint4*)(h2s + (tj * 2 + rr) * 256 + ((hc ^ (tj & 7)) << 3));
                uc[rr][0] = v.x; uc[rr][1] = v.y; uc[rr][2] = v.z; uc[rr][3] = v.w;
            }
            v = *(const uint4*)(w2s + hc * 4);
            uw[0] = v.x; uw[1] = v.y; uw[2] = v.z; uw[3] = v.w;
        }
        #pragma unroll
        for (int e = 0; e < 4; e++){
            const f16x2 wv = __builtin_bit_cast(f16x2, uw[e]);
            #pragma unroll
            for (int ii = 0; ii < 4; ii++){
                const f16x2 av = __builtin_bit_cast(f16x2, ua[ii][e]);
                #pragma unroll
                for (int jj = 0; jj < 2; jj++){
                    const f16x2 cv = __builtin_bit_cast(f16x2, uc[jj][e]);
                    f16x2 x = av + cv;
                    x = __builtin_elementwise_max(x, (f16x2)((_Float16)0.0f));
                    acc[ii][jj] = fdot2(x, wv, acc[ii][jj]);
                }
            }
        }
    }
    const float bb = b2[0];
    #pragma unroll
    for (int ii = 0; ii < 4; ii++){
        const int i = i0 + ti * 4 + ii;
        float2 o;
        o.x = 1.0f / (1.0f + __expf(-(acc[ii][0] + bb)));
        o.y = 1.0f / (1.0f + __expf(-(acc[ii][1] + bb)));
        *(float2*)(outM + (size_t)(b * LL + i) * LL + j0 + tj * 2) = o;
    }
}

extern "C" void kernel_launch(void* const* d_in, const int* in_sizes, int n_in,
                              void* d_out, int out_size, void* d_ws, size_t ws_size,
                              hipStream_t stream)
{
    const float* e1  = (const float*)d_in[0];
    const float* e2  = (const float*)d_in[1];
    const float* ipw = (const float*)d_in[2];
    const float* ipb = (const float*)d_in[3];
    const float* W1  = (const float*)d_in[4];
    const float* b1  = (const float*)d_in[5];
    const float* W2  = (const float*)d_in[6];
    const float* b2  = (const float*)d_in[7];
    float* outA = (float*)d_out;                       // (B,L1,L2) attn weights
    float* outM = outA + (size_t)2 * LL * LL;          // (B,L1,L2) match scores

    _Float16* ws  = (_Float16*)d_ws;
    _Float16* wq  = ws;                  // 1024x256 f16 (q, pre-scaled)
    _Float16* wk  = ws + 262144;         // k
    _Float16* wh1 = ws + 524288;         // h1
    _Float16* wh2 = ws + 786432;         // h2 + b1

    hipLaunchKernelGGL(k_proj,  dim3(256), dim3(256), 0, stream,
                       e1, e2, ipw, ipb, W1, b1, wq, wk, wh1, wh2);
    hipLaunchKernelGGL(k_attn,  dim3(64),  dim3(256), 0, stream, wq, wk, outA);
    hipLaunchKernelGGL(k_match, dim3(256), dim3(256), 0, stream,
                       wh1, wh2, W2, b2, outM);
}

// Round 7
// 97.250 us; speedup vs baseline: 1.2030x; 1.1454x over previous
//
#include <hip/hip_runtime.h>
#include <hip/hip_fp16.h>
#include <stdint.h>

typedef _Float16 f16x8 __attribute__((ext_vector_type(8)));
typedef _Float16 f16x2 __attribute__((ext_vector_type(2)));
typedef float f32x4 __attribute__((ext_vector_type(4)));

#define LL 512
#define HH 256

__device__ __forceinline__ unsigned pkrtz(float a, float b){
    return __builtin_bit_cast(unsigned, __builtin_amdgcn_cvt_pkrtz(a, b));
}

#if __has_builtin(__builtin_amdgcn_fdot2)
__device__ __forceinline__ float fdot2(f16x2 x, f16x2 w, float acc){
    return __builtin_amdgcn_fdot2(x, w, acc, false);
}
#else
__device__ __forceinline__ float fdot2(f16x2 x, f16x2 w, float acc){
    return fmaf((float)x[0], (float)w[0], fmaf((float)x[1], (float)w[1], acc));
}
#endif

// ---------------------------------------------------------------------------
// K1: four projections as MFMA f16 GEMMs (verified round 4, unchanged).
// ---------------------------------------------------------------------------
__global__ __launch_bounds__(256) void k_proj(
    const float* __restrict__ e1, const float* __restrict__ e2,
    const float* __restrict__ ipw, const float* __restrict__ ipb,
    const float* __restrict__ W1, const float* __restrict__ b1,
    _Float16* __restrict__ wq, _Float16* __restrict__ wk,
    _Float16* __restrict__ wh1, _Float16* __restrict__ wh2)
{
    __shared__ __align__(16) _Float16 As[64 * 256];
    __shared__ __align__(16) _Float16 Bs[64 * 256];
    const int t = threadIdx.x;
    const int blk = blockIdx.x;
    const int g = blk >> 6, mt = (blk >> 2) & 15, nt = blk & 3;
    const int m0 = mt * 64, n0 = nt * 64;
    const float* abase = (g == 0 || g == 2) ? e1 : e2;
    const float* bbase; int bstride;
    if (g == 0)      { bbase = ipw;         bstride = 256; }
    else if (g == 1) { bbase = ipw + 65536; bstride = 256; }
    else if (g == 2) { bbase = W1;          bstride = 512; }
    else             { bbase = W1 + 256;    bstride = 512; }

    #pragma unroll
    for (int s = 0; s < 8; s++){
        const int c = s * 256 + t;
        const int row = c >> 5, kg = c & 31;
        const int dst = row * 256 + ((kg ^ (row & 7)) << 3);
        {
            const float4* sa = (const float4*)(abase + (size_t)(m0 + row) * 256 + kg * 8);
            float4 a0 = sa[0], a1 = sa[1];
            uint4 pk = { pkrtz(a0.x, a0.y), pkrtz(a0.z, a0.w),
                         pkrtz(a1.x, a1.y), pkrtz(a1.z, a1.w) };
            *(uint4*)(As + dst) = pk;
        }
        {
            const float4* sb = (const float4*)(bbase + (size_t)(n0 + row) * bstride + kg * 8);
            float4 b0 = sb[0], b1v = sb[1];
            uint4 pk = { pkrtz(b0.x, b0.y), pkrtz(b0.z, b0.w),
                         pkrtz(b1v.x, b1v.y), pkrtz(b1v.z, b1v.w) };
            *(uint4*)(Bs + dst) = pk;
        }
    }
    __syncthreads();
    const int w = t >> 6, l = t & 63;
    const int lr = l & 15, lg = l >> 4;
    f32x4 acc[4] = {};
    const int brow = w * 16 + lr;
    #pragma unroll
    for (int kk = 0; kk < 8; kk++){
        const int cb = ((kk * 4 + lg) ^ (lr & 7)) << 3;   // swizzled 16B chunk
        f16x8 bf = *(const f16x8*)(Bs + brow * 256 + cb);
        #pragma unroll
        for (int ms = 0; ms < 4; ms++){
            f16x8 af = *(const f16x8*)(As + (ms * 16 + lr) * 256 + cb);
            acc[ms] = __builtin_amdgcn_mfma_f32_16x16x32_f16(af, bf, acc[ms], 0, 0, 0);
        }
    }
    const int n = n0 + w * 16 + lr;
    float bias = 0.f, scale = 1.f;
    if (g == 0)      { bias = ipb[n];       scale = 0.17677669529663689f; }
    else if (g == 1) { bias = ipb[256 + n]; }
    else if (g == 3) { bias = b1[n]; }
    _Float16* outp = (g == 0) ? wq : ((g == 1) ? wk : ((g == 2) ? wh1 : wh2));
    #pragma unroll
    for (int ms = 0; ms < 4; ms++)
        #pragma unroll
        for (int r = 0; r < 4; r++){
            const int m = m0 + ms * 16 + lg * 4 + r;
            outp[(size_t)m * 256 + n] = (_Float16)((acc[ms][r] + bias) * scale);
        }
}

// ---------------------------------------------------------------------------
// K2a: logits[b,h,i,j] = qh . kh (scale pre-folded into q), f16 out.
// grid = b x h x it x jt = 2*8*8*8 = 1024 blocks (4/CU), 256 thr.
// No LDS: Q/K frags straight from L1/L2 (1 MB working set). 4 MFMA/wave.
// C-layout (verified via k_proj): col = lane&15 <-> B-row, row = (lane>>4)*4+r.
// ---------------------------------------------------------------------------
__global__ __launch_bounds__(256) void k_logits(
    const _Float16* __restrict__ wq, const _Float16* __restrict__ wk,
    _Float16* __restrict__ lg)
{
    const int t = threadIdx.x;
    const int blk = blockIdx.x;
    const int jt = blk & 7, it = (blk >> 3) & 7, h = (blk >> 6) & 7, b = blk >> 9;
    const int w = t >> 6, l = t & 63, lr = l & 15, lg2 = l >> 4;
    const int i0 = it * 64 + w * 16, j0 = jt * 64;
    const f32x4 zero = {};
    f16x8 af = *(const f16x8*)(wq + (size_t)(b * LL + i0 + lr) * HH + h * 32 + lg2 * 8);
    f32x4 acc[4];
    #pragma unroll
    for (int jb = 0; jb < 4; jb++){
        f16x8 bf = *(const f16x8*)(wk + (size_t)(b * LL + j0 + jb * 16 + lr) * HH + h * 32 + lg2 * 8);
        acc[jb] = __builtin_amdgcn_mfma_f32_16x16x32_f16(af, bf, zero, 0, 0, 0);
    }
    _Float16* orow = lg + ((size_t)(b * 8 + h) * LL + i0 + lg2 * 4) * LL + j0 + lr;
    #pragma unroll
    for (int jb = 0; jb < 4; jb++)
        #pragma unroll
        for (int r = 0; r < 4; r++)
            orow[(size_t)r * LL + jb * 16] = (_Float16)acc[jb][r];
}

// ---------------------------------------------------------------------------
// K2b: per (b,i) row: 8 no-max softmaxes over j (exp is f32-safe: |logit|<~45)
// + head-mean. grid = 1024 blocks, 256 thr; thread owns j in {2t, 2t+1}.
// ---------------------------------------------------------------------------
__global__ __launch_bounds__(256) void k_smmean(
    const _Float16* __restrict__ lg, float* __restrict__ outA)
{
    __shared__ float ps[4][8];
    __shared__ float inv[8];
    const int t = threadIdx.x;
    const int bi = blockIdx.x;              // b*512 + i
    const int b = bi >> 9, i = bi & 511;
    const int w = t >> 6;
    const size_t base = (size_t)(b * 8) * LL * LL + (size_t)i * LL + 2 * t;
    float e[8][2], p[8];
    #pragma unroll
    for (int h = 0; h < 8; h++){
        f16x2 u = *(const f16x2*)(lg + base + (size_t)h * LL * LL);
        e[h][0] = __expf((float)u[0]);
        e[h][1] = __expf((float)u[1]);
        p[h] = e[h][0] + e[h][1];
    }
    #pragma unroll
    for (int h = 0; h < 8; h++){
        float s = p[h];
        #pragma unroll
        for (int mask = 1; mask < 64; mask <<= 1) s += __shfl_xor(s, mask, 64);
        if ((t & 63) == 0) ps[w][h] = s;
    }
    __syncthreads();
    if (t < 8) inv[t] = 1.0f / (8.0f * (ps[0][t] + ps[1][t] + ps[2][t] + ps[3][t]));
    __syncthreads();
    float iv[8];
    #pragma unroll
    for (int h = 0; h < 8; h++) iv[h] = inv[h];
    float2 o; o.x = 0.f; o.y = 0.f;
    #pragma unroll
    for (int h = 0; h < 8; h++){
        o.x = fmaf(e[h][0], iv[h], o.x);
        o.y = fmaf(e[h][1], iv[h], o.y);
    }
    *(float2*)(outA + (size_t)bi * LL + 2 * t) = o;
}

// ---------------------------------------------------------------------------
// K4: match_scores (verified round 4, unchanged).
// ---------------------------------------------------------------------------
__global__ __launch_bounds__(256) void k_match(
    const _Float16* __restrict__ wh1, const _Float16* __restrict__ wh2,
    const float* __restrict__ W2, const float* __restrict__ b2,
    float* __restrict__ outM)
{
    __shared__ __align__(16) _Float16 h1s[64 * 256];
    __shared__ __align__(16) _Float16 h2s[32 * 256];
    __shared__ __align__(16) f16x2 w2s[128];
    const int t = threadIdx.x;
    const int blk = blockIdx.x;
    const int b = blk >> 7, it = (blk >> 4) & 7, jt = blk & 15;
    const int i0 = it * 64, j0 = jt * 32;
    if (t < 128){
        unsigned pk = pkrtz(W2[2 * t], W2[2 * t + 1]);
        w2s[t] = __builtin_bit_cast(f16x2, pk);
    }
    #pragma unroll
    for (int s = 0; s < 8; s++){
        const int c = s * 256 + t;
        const int row = c >> 5, hc = c & 31;
        uint4 v = *(const uint4*)(wh1 + (size_t)(b * LL + i0 + row) * HH + hc * 8);
        *(uint4*)(h1s + row * 256 + ((hc ^ ((row >> 2) & 7)) << 3)) = v;
    }
    #pragma unroll
    for (int s = 0; s < 4; s++){
        const int c = s * 256 + t;
        const int row = c >> 5, hc = c & 31;
        uint4 v = *(const uint4*)(wh2 + (size_t)(b * LL + j0 + row) * HH + hc * 8);
        *(uint4*)(h2s + row * 256 + ((hc ^ ((row >> 1) & 7)) << 3)) = v;
    }
    __syncthreads();
    const int ti = t >> 4, tj = t & 15;
    float acc[4][2] = {};
    for (int hc = 0; hc < 32; hc++){
        unsigned ua[4][4], uc[2][4], uw[4];
        {
            uint4 v;
            #pragma unroll
            for (int rr = 0; rr < 4; rr++){
                v = *(const uint4*)(h1s + (ti * 4 + rr) * 256 + ((hc ^ (ti & 7)) << 3));
                ua[rr][0] = v.x; ua[rr][1] = v.y; ua[rr][2] = v.z; ua[rr][3] = v.w;
            }
            #pragma unroll
            for (int rr = 0; rr < 2; rr++){
                v = *(const uint4*)(h2s + (tj * 2 + rr) * 256 + ((hc ^ (tj & 7)) << 3));
                uc[rr][0] = v.x; uc[rr][1] = v.y; uc[rr][2] = v.z; uc[rr][3] = v.w;
            }
            v = *(const uint4*)(w2s + hc * 4);
            uw[0] = v.x; uw[1] = v.y; uw[2] = v.z; uw[3] = v.w;
        }
        #pragma unroll
        for (int e = 0; e < 4; e++){
            const f16x2 wv = __builtin_bit_cast(f16x2, uw[e]);
            #pragma unroll
            for (int ii = 0; ii < 4; ii++){
                const f16x2 av = __builtin_bit_cast(f16x2, ua[ii][e]);
                #pragma unroll
                for (int jj = 0; jj < 2; jj++){
                    const f16x2 cv = __builtin_bit_cast(f16x2, uc[jj][e]);
                    f16x2 x = av + cv;
                    x = __builtin_elementwise_max(x, (f16x2)((_Float16)0.0f));
                    acc[ii][jj] = fdot2(x, wv, acc[ii][jj]);
                }
            }
        }
    }
    const float bb = b2[0];
    #pragma unroll
    for (int ii = 0; ii < 4; ii++){
        const int i = i0 + ti * 4 + ii;
        float2 o;
        o.x = 1.0f / (1.0f + __expf(-(acc[ii][0] + bb)));
        o.y = 1.0f / (1.0f + __expf(-(acc[ii][1] + bb)));
        *(float2*)(outM + (size_t)(b * LL + i) * LL + j0 + tj * 2) = o;
    }
}

extern "C" void kernel_launch(void* const* d_in, const int* in_sizes, int n_in,
                              void* d_out, int out_size, void* d_ws, size_t ws_size,
                              hipStream_t stream)
{
    const float* e1  = (const float*)d_in[0];
    const float* e2  = (const float*)d_in[1];
    const float* ipw = (const float*)d_in[2];
    const float* ipb = (const float*)d_in[3];
    const float* W1  = (const float*)d_in[4];
    const float* b1  = (const float*)d_in[5];
    const float* W2  = (const float*)d_in[6];
    const float* b2  = (const float*)d_in[7];
    float* outA = (float*)d_out;                       // (B,L1,L2) attn weights
    float* outM = outA + (size_t)2 * LL * LL;          // (B,L1,L2) match scores

    _Float16* ws  = (_Float16*)d_ws;
    _Float16* wq  = ws;                  // 1024x256 f16 (q, pre-scaled)
    _Float16* wk  = ws + 262144;         // k
    _Float16* wh1 = ws + 524288;         // h1
    _Float16* wh2 = ws + 786432;         // h2 + b1
    _Float16* lg  = ws + 1048576;        // logits (b,h,i,j): 4.19M f16

    hipLaunchKernelGGL(k_proj,   dim3(256),  dim3(256), 0, stream,
                       e1, e2, ipw, ipb, W1, b1, wq, wk, wh1, wh2);
    hipLaunchKernelGGL(k_logits, dim3(1024), dim3(256), 0, stream, wq, wk, lg);
    hipLaunchKernelGGL(k_smmean, dim3(1024), dim3(256), 0, stream, lg, outA);
    hipLaunchKernelGGL(k_match,  dim3(256),  dim3(256), 0, stream,
                       wh1, wh2, W2, b2, outM);
}

// Round 9
// 96.355 us; speedup vs baseline: 1.2142x; 1.0093x over previous
//
#include <hip/hip_runtime.h>
#include <hip/hip_fp16.h>
#include <stdint.h>

typedef _Float16 f16x8 __attribute__((ext_vector_type(8)));
typedef _Float16 f16x2 __attribute__((ext_vector_type(2)));
typedef float f32x4 __attribute__((ext_vector_type(4)));

#define LL 512
#define HH 256
#define LGS 516   // logits LDS row stride (elems): 516 % 16 == 4 -> lane-group i-steps 8 banks apart

__device__ __forceinline__ unsigned pkrtz(float a, float b){
    return __builtin_bit_cast(unsigned, __builtin_amdgcn_cvt_pkrtz(a, b));
}

#if __has_builtin(__builtin_amdgcn_fdot2)
__device__ __forceinline__ float fdot2(f16x2 x, f16x2 w, float acc){
    return __builtin_amdgcn_fdot2(x, w, acc, false);
}
#else
__device__ __forceinline__ float fdot2(f16x2 x, f16x2 w, float acc){
    return fmaf((float)x[0], (float)w[0], fmaf((float)x[1], (float)w[1], acc));
}
#endif

// ---------------------------------------------------------------------------
// K1: four projections as MFMA f16 GEMMs (verified rounds 4/7, unchanged).
// ---------------------------------------------------------------------------
__global__ __launch_bounds__(256) void k_proj(
    const float* __restrict__ e1, const float* __restrict__ e2,
    const float* __restrict__ ipw, const float* __restrict__ ipb,
    const float* __restrict__ W1, const float* __restrict__ b1,
    _Float16* __restrict__ wq, _Float16* __restrict__ wk,
    _Float16* __restrict__ wh1, _Float16* __restrict__ wh2)
{
    __shared__ __align__(16) _Float16 As[64 * 256];
    __shared__ __align__(16) _Float16 Bs[64 * 256];
    const int t = threadIdx.x;
    const int blk = blockIdx.x;
    const int g = blk >> 6, mt = (blk >> 2) & 15, nt = blk & 3;
    const int m0 = mt * 64, n0 = nt * 64;
    const float* abase = (g == 0 || g == 2) ? e1 : e2;
    const float* bbase; int bstride;
    if (g == 0)      { bbase = ipw;         bstride = 256; }
    else if (g == 1) { bbase = ipw + 65536; bstride = 256; }
    else if (g == 2) { bbase = W1;          bstride = 512; }
    else             { bbase = W1 + 256;    bstride = 512; }

    #pragma unroll
    for (int s = 0; s < 8; s++){
        const int c = s * 256 + t;
        const int row = c >> 5, kg = c & 31;
        const int dst = row * 256 + ((kg ^ (row & 7)) << 3);
        {
            const float4* sa = (const float4*)(abase + (size_t)(m0 + row) * 256 + kg * 8);
            float4 a0 = sa[0], a1 = sa[1];
            uint4 pk = { pkrtz(a0.x, a0.y), pkrtz(a0.z, a0.w),
                         pkrtz(a1.x, a1.y), pkrtz(a1.z, a1.w) };
            *(uint4*)(As + dst) = pk;
        }
        {
            const float4* sb = (const float4*)(bbase + (size_t)(n0 + row) * bstride + kg * 8);
            float4 b0 = sb[0], b1v = sb[1];
            uint4 pk = { pkrtz(b0.x, b0.y), pkrtz(b0.z, b0.w),
                         pkrtz(b1v.x, b1v.y), pkrtz(b1v.z, b1v.w) };
            *(uint4*)(Bs + dst) = pk;
        }
    }
    __syncthreads();
    const int w = t >> 6, l = t & 63;
    const int lr = l & 15, lg = l >> 4;
    f32x4 acc[4] = {};
    const int brow = w * 16 + lr;
    #pragma unroll
    for (int kk = 0; kk < 8; kk++){
        const int cb = ((kk * 4 + lg) ^ (lr & 7)) << 3;   // swizzled 16B chunk
        f16x8 bf = *(const f16x8*)(Bs + brow * 256 + cb);
        #pragma unroll
        for (int ms = 0; ms < 4; ms++){
            f16x8 af = *(const f16x8*)(As + (ms * 16 + lr) * 256 + cb);
            acc[ms] = __builtin_amdgcn_mfma_f32_16x16x32_f16(af, bf, acc[ms], 0, 0, 0);
        }
    }
    const int n = n0 + w * 16 + lr;
    float bias = 0.f, scale = 1.f;
    if (g == 0)      { bias = ipb[n];       scale = 0.17677669529663689f; }
    else if (g == 1) { bias = ipb[256 + n]; }
    else if (g == 3) { bias = b1[n]; }
    _Float16* outp = (g == 0) ? wq : ((g == 1) ? wk : ((g == 2) ? wh1 : wh2));
    #pragma unroll
    for (int ms = 0; ms < 4; ms++)
        #pragma unroll
        for (int r = 0; r < 4; r++){
            const int m = m0 + ms * 16 + lg * 4 + r;
            outp[(size_t)m * 256 + n] = (_Float16)((acc[ms][r] + bias) * scale);
        }
}

// ---------------------------------------------------------------------------
// K2 (fused): logits + no-max softmax + head-mean, logits live in LDS only.
// grid = B*32 = 64 blocks x 512 thr (8 waves, 2/SIMD). Wave w owns j-range
// [w*64, w*64+64). Pass 1: QK^T MFMA per h -> f16 logit to LDS + exp-sum
// partials (on the f16-rounded value, consistent with pass 2). Cross-wave
// combine. Pass 2: wave w re-reads rows i=2w,2w+1 across all j (conflict-free
// f16x2 reads), exp * inv, coalesced float2 stores.
// No-max softmax is exact (shift-invariance); |logits| << 88 so f32 exp safe.
// ---------------------------------------------------------------------------
__global__ __launch_bounds__(512) void k_attn(
    const _Float16* __restrict__ wq, const _Float16* __restrict__ wk,
    float* __restrict__ outA)
{
    __shared__ __align__(16) _Float16 lgs[8 * 16 * LGS];   // 129 KB
    __shared__ float part[8][8][16];                        // [wave][h][i]
    __shared__ float inv[8][16];                            // [h][i]
    const int t = threadIdx.x;
    const int b = blockIdx.x >> 5;
    const int i0 = (blockIdx.x & 31) << 4;
    const int w = t >> 6, l = t & 63, lr = l & 15, lg2 = l >> 4;
    const int j0 = w * 64;
    const f32x4 zero = {};

    for (int h = 0; h < 8; h++){
        f16x8 q = *(const f16x8*)(wq + (size_t)(b * LL + i0 + lr) * HH + h * 32 + lg2 * 8);
        float s4[4] = {0.f, 0.f, 0.f, 0.f};
        #pragma unroll
        for (int jb = 0; jb < 4; jb++){
            f16x8 kf = *(const f16x8*)(wk + (size_t)(b * LL + j0 + jb * 16 + lr) * HH + h * 32 + lg2 * 8);
            f32x4 a = __builtin_amdgcn_mfma_f32_16x16x32_f16(q, kf, zero, 0, 0, 0);
            #pragma unroll
            for (int r = 0; r < 4; r++){
                _Float16 lf = (_Float16)a[r];
                lgs[(h * 16 + lg2 * 4 + r) * LGS + j0 + jb * 16 + lr] = lf;
                s4[r] += __expf((float)lf);
            }
        }
        #pragma unroll
        for (int r = 0; r < 4; r++){
            #pragma unroll
            for (int mask = 1; mask < 16; mask <<= 1)
                s4[r] += __shfl_xor(s4[r], mask, 64);
        }
        if (lr == 0){
            #pragma unroll
            for (int r = 0; r < 4; r++) part[w][h][lg2 * 4 + r] = s4[r];
        }
    }
    __syncthreads();
    if (t < 128){
        const int h = t >> 4, i = t & 15;
        float s = 0.f;
        #pragma unroll
        for (int ww = 0; ww < 8; ww++) s += part[ww][h][i];
        inv[h][i] = 1.0f / (8.0f * s);
    }
    __syncthreads();
    // pass 2: wave w -> rows 2w, 2w+1; lane l -> j pairs {2l+128k, 2l+1+128k}
    #pragma unroll
    for (int dp = 0; dp < 2; dp++){
        const int ii = w * 2 + dp;
        float iv[8];
        #pragma unroll
        for (int h = 0; h < 8; h++) iv[h] = inv[h][ii];
        float* orow = outA + (size_t)(b * LL + i0 + ii) * LL;
        #pragma unroll
        for (int k = 0; k < 4; k++){
            const int j = 2 * l + 128 * k;
            float2 o; o.x = 0.f; o.y = 0.f;
            #pragma unroll
            for (int h = 0; h < 8; h++){
                f16x2 u = *(const f16x2*)(lgs + (h * 16 + ii) * LGS + j);
                o.x = fmaf(__expf((float)u[0]), iv[h], o.x);
                o.y = fmaf(__expf((float)u[1]), iv[h], o.y);
            }
            *(float2*)(orow + j) = o;
        }
    }
}

// ---------------------------------------------------------------------------
// K4: match_scores = sigmoid( sum_h relu(h1[i,h]+h2b[j,h]) . w2[h] + b2 )
// grid = 2 x 16 x 16 = 512 blocks (32i x 32j tile, 2 blocks/CU), 256 thr,
// per-thread 4i x 1j. Per hc: 4 broadcast h1 reads + 1 swizzled h2 read +
// 1 w2 broadcast = 6 ds_read_b128 vs 48 packed-VALU -> VALU-bound with
// 2 waves/SIMD hiding.
// ---------------------------------------------------------------------------
__global__ __launch_bounds__(256) void k_match(
    const _Float16* __restrict__ wh1, const _Float16* __restrict__ wh2,
    const float* __restrict__ W2, const float* __restrict__ b2,
    float* __restrict__ outM)
{
    __shared__ __align__(16) _Float16 h1s[32 * 256];
    __shared__ __align__(16) _Float16 h2s[32 * 256];
    __shared__ __align__(16) f16x2 w2s[128];
    const int t = threadIdx.x;
    const int blk = blockIdx.x;
    const int b = blk >> 8, it = (blk >> 4) & 15, jt = blk & 15;
    const int i0 = it * 32, j0 = jt * 32;
    if (t < 128){
        unsigned pk = pkrtz(W2[2 * t], W2[2 * t + 1]);
        w2s[t] = __builtin_bit_cast(f16x2, pk);
    }
    #pragma unroll
    for (int s = 0; s < 4; s++){
        const int c = s * 256 + t;
        const int row = c >> 5, hc = c & 31;
        const int dst = row * 256 + ((hc ^ (row & 7)) << 3);
        *(uint4*)(h1s + dst) = *(const uint4*)(wh1 + (size_t)(b * LL + i0 + row) * HH + hc * 8);
        *(uint4*)(h2s + dst) = *(const uint4*)(wh2 + (size_t)(b * LL + j0 + row) * HH + hc * 8);
    }
    __syncthreads();
    const int ti = t >> 5, tj = t & 31;
    float acc[4] = {0.f, 0.f, 0.f, 0.f};
    #pragma unroll 4
    for (int hc = 0; hc < 32; hc++){
        uint4 va[4];
        #pragma unroll
        for (int rr = 0; rr < 4; rr++){
            const int row = ti * 4 + rr;
            va[rr] = *(const uint4*)(h1s + row * 256 + ((hc ^ (row & 7)) << 3));
        }
        uint4 vc = *(const uint4*)(h2s + tj * 256 + ((hc ^ (tj & 7)) << 3));
        uint4 vw = *(const uint4*)(w2s + hc * 4);
        const unsigned uc_[4] = {vc.x, vc.y, vc.z, vc.w};
        const unsigned uw_[4] = {vw.x, vw.y, vw.z, vw.w};
        #pragma unroll
        for (int rr = 0; rr < 4; rr++){
            const unsigned ue[4] = {va[rr].x, va[rr].y, va[rr].z, va[rr].w};
            #pragma unroll
            for (int e = 0; e < 4; e++){
                f16x2 x = __builtin_bit_cast(f16x2, ue[e]) + __builtin_bit_cast(f16x2, uc_[e]);
                x = __builtin_elementwise_max(x, (f16x2)((_Float16)0.0f));
                acc[rr] = fdot2(x, __builtin_bit_cast(f16x2, uw_[e]), acc[rr]);
            }
        }
    }
    const float bb = b2[0];
    #pragma unroll
    for (int rr = 0; rr < 4; rr++){
        outM[(size_t)(b * LL + i0 + ti * 4 + rr) * LL + j0 + tj] =
            1.0f / (1.0f + __expf(-(acc[rr] + bb)));
    }
}

extern "C" void kernel_launch(void* const* d_in, const int* in_sizes, int n_in,
                              void* d_out, int out_size, void* d_ws, size_t ws_size,
                              hipStream_t stream)
{
    const float* e1  = (const float*)d_in[0];
    const float* e2  = (const float*)d_in[1];
    const float* ipw = (const float*)d_in[2];
    const float* ipb = (const float*)d_in[3];
    const float* W1  = (const float*)d_in[4];
    const float* b1  = (const float*)d_in[5];
    const float* W2  = (const float*)d_in[6];
    const float* b2  = (const float*)d_in[7];
    float* outA = (float*)d_out;                       // (B,L1,L2) attn weights
    float* outM = outA + (size_t)2 * LL * LL;          // (B,L1,L2) match scores

    _Float16* ws  = (_Float16*)d_ws;
    _Float16* wq  = ws;                  // 1024x256 f16 (q, pre-scaled)
    _Float16* wk  = ws + 262144;         // k
    _Float16* wh1 = ws + 524288;         // h1
    _Float16* wh2 = ws + 786432;         // h2 + b1

    hipLaunchKernelGGL(k_proj,  dim3(256), dim3(256), 0, stream,
                       e1, e2, ipw, ipb, W1, b1, wq, wk, wh1, wh2);
    hipLaunchKernelGGL(k_attn,  dim3(64),  dim3(512), 0, stream, wq, wk, outA);
    hipLaunchKernelGGL(k_match, dim3(512), dim3(256), 0, stream,
                       wh1, wh2, W2, b2, outM);
}